// Round 1
// 1153.694 us; speedup vs baseline: 1.4226x; 1.4226x over previous
//
#include <hip/hip_runtime.h>
#include <stdint.h>

// out[M,N] = x[M,K] @ w[N,K]^T * scale
#define MM 8192
#define NN 11008
#define KK 4096

#define BM 256
#define BN 256
#define BK 64
#define KT (KK / BK)    // 64 K-tiles
#define NIT (KT / 2)    // 32 iterations (2 K-tiles each)

typedef short short8 __attribute__((ext_vector_type(8)));
typedef unsigned short ushort8 __attribute__((ext_vector_type(8)));
typedef float floatx4 __attribute__((ext_vector_type(4)));

__device__ __forceinline__ unsigned short f2bf(float f) {
    unsigned int u = __float_as_uint(f);
    u += 0x7fffu + ((u >> 16) & 1u);   // RNE
    return (unsigned short)(u >> 16);
}

// ---- fp32 -> bf16 conversion (8 elems/thread) ----
__global__ __launch_bounds__(256) void cvt_x_kernel(const float* __restrict__ in,
                                                    unsigned short* __restrict__ out) {
    const size_t i = ((size_t)blockIdx.x * 256 + threadIdx.x) * 8;
    const float4 v0 = *(const float4*)(in + i);
    const float4 v1 = *(const float4*)(in + i + 4);
    ushort8 r;
    r[0] = f2bf(v0.x); r[1] = f2bf(v0.y); r[2] = f2bf(v0.z); r[3] = f2bf(v0.w);
    r[4] = f2bf(v1.x); r[5] = f2bf(v1.y); r[6] = f2bf(v1.z); r[7] = f2bf(v1.w);
    *(ushort8*)(out + i) = r;
}

// ---- int32 (int8-range) -> bf16 conversion, exact (8 elems/thread) ----
__global__ __launch_bounds__(256) void cvt_w_kernel(const int* __restrict__ in,
                                                    unsigned short* __restrict__ out) {
    const size_t i = ((size_t)blockIdx.x * 256 + threadIdx.x) * 8;
    const int4 v0 = *(const int4*)(in + i);
    const int4 v1 = *(const int4*)(in + i + 4);
    ushort8 r;
    r[0] = f2bf((float)v0.x); r[1] = f2bf((float)v0.y);
    r[2] = f2bf((float)v0.z); r[3] = f2bf((float)v0.w);
    r[4] = f2bf((float)v1.x); r[5] = f2bf((float)v1.y);
    r[6] = f2bf((float)v1.z); r[7] = f2bf((float)v1.w);
    *(ushort8*)(out + i) = r;
}

// ============================================================================
// 256x256 8-phase bf16 GEMM (m201 template): BK=64, 8 waves (2Mx4N), 512 thr.
// LDS 128 KiB = 2 dbuf x {A,B} x 2 half-tile slots x 16 KiB.
//   A slot h (elements [h*8192, +8192)): layout [kc:2][row:128][32 k-cols],
//     slot-row sr -> tile row (sr>>6)*128 + h*64 + (sr&63)   (quarter pairs)
//   B slot h (base +16384): slot-row sc -> tile col (sc>>5)*64 + h*32 + (sc&31)
// st_16x32 swizzle (element units): eoff ^= ((eoff>>8)&1)<<4, applied on the
// ds_read address AND (inverse, same involution) on the global staging source;
// global_load_lds dest stays linear (wave-uniform base + lane*16B).
// Phases (quadrant order Q(rq,cq) = 00,01,10,11 per K-tile; B frags held in
// regs so B slots free after their single read; A re-reads avoided):
//   ph1: LDA(rq0)+LDB(cq0) [12 rd] | stage buf1-A-h1 (tile 2i+1) | MFMA Q00
//   ph2: LDB(cq1)           [4 rd] | stage buf0-A-h0 (tile 2i+2) | MFMA Q01
//   ph3: LDA(rq1)           [8 rd] | stage buf0-B-h0             | MFMA Q10
//   ph4:                    [0 rd] | stage buf0-B-h1 | vmcnt(6)  | MFMA Q11
//   ph5..8: same on buf1, staging buf0-A-h1 then buf1 slots of tile 2i+3.
// vmcnt(6) = 3 half-tiles (6 loads) in flight, never drained in main loop.
// ============================================================================

#define GLL(SRC, DSTE) __builtin_amdgcn_global_load_lds( \
    (const __attribute__((address_space(1))) void*)(SRC), \
    (__attribute__((address_space(3))) void*)(lds + (DSTE)), 16, 0, 0)

#define STAGE_A(BUF, H, TILE) do { \
    GLL(Ag + offA0 + (size_t)(H) * (64 * KK) + (TILE) * 64, (BUF) * 32768 + (H) * 8192 + wave * 1024); \
    GLL(Ag + offA1 + (size_t)(H) * (64 * KK) + (TILE) * 64, (BUF) * 32768 + (H) * 8192 + wave * 1024 + 512); \
} while (0)

#define STAGE_B(BUF, H, TILE) do { \
    GLL(Bg + offB0 + (size_t)(H) * (32 * KK) + (TILE) * 64, (BUF) * 32768 + 16384 + (H) * 8192 + wave * 1024); \
    GLL(Bg + offB1 + (size_t)(H) * (32 * KK) + (TILE) * 64, (BUF) * 32768 + 16384 + (H) * 8192 + wave * 1024 + 512); \
} while (0)

#define LDA(BUFE, RQ) do { \
    _Pragma("unroll") for (int rb_ = 0; rb_ < 4; ++rb_) \
    _Pragma("unroll") for (int kc_ = 0; kc_ < 2; ++kc_) \
        a[rb_][kc_] = *(const short8*)(lds + (BUFE) + (RQ) * 8192 + kc_ * 4096 + rb_ * 512 + aRd); \
} while (0)

#define LDB(BUFE, CQ, DST) do { \
    _Pragma("unroll") for (int cb_ = 0; cb_ < 2; ++cb_) \
    _Pragma("unroll") for (int kc_ = 0; kc_ < 2; ++kc_) \
        DST[cb_][kc_] = *(const short8*)(lds + (BUFE) + (CQ) * 8192 + kc_ * 4096 + cb_ * 512 + bRd); \
} while (0)

#define MFMA_Q(RQ, CQ, BREG) do { \
    _Pragma("unroll") for (int rb_ = 0; rb_ < 4; ++rb_) \
    _Pragma("unroll") for (int cb_ = 0; cb_ < 2; ++cb_) \
    _Pragma("unroll") for (int kc_ = 0; kc_ < 2; ++kc_) \
        acc[RQ][rb_][CQ][cb_] = __builtin_amdgcn_mfma_f32_16x16x32_bf16( \
            a[rb_][kc_], BREG[cb_][kc_], acc[RQ][rb_][CQ][cb_], 0, 0, 0); \
} while (0)

#define BAR()       asm volatile("s_barrier" ::: "memory")
#define WAIT_LGKM() asm volatile("s_waitcnt lgkmcnt(0)" ::: "memory")
#define WAIT_VM6()  asm volatile("s_waitcnt vmcnt(6) lgkmcnt(0)" ::: "memory")
#define WAIT_VM0()  asm volatile("s_waitcnt vmcnt(0) lgkmcnt(0)" ::: "memory")
#define PRIO1()     __builtin_amdgcn_s_setprio(1)
#define PRIO0()     __builtin_amdgcn_s_setprio(0)

__global__ __launch_bounds__(512, 2) void gemm_bt_bf16_8ph(
    const unsigned short* __restrict__ A,   // [MM, KK] bf16 bits
    const unsigned short* __restrict__ B,   // [NN, KK] bf16 bits
    const float* __restrict__ scale_p,
    float* __restrict__ C)                  // [MM, NN] fp32
{
    __shared__ unsigned short lds[65536];   // 128 KiB

    const int tid  = threadIdx.x;
    const int lane = tid & 63;
    const int wave = tid >> 6;      // 0..7
    const int wr   = wave >> 2;     // 0..1 : 128 output rows each
    const int wc   = wave & 3;      // 0..3 : 64 output cols each

    const int bm = blockIdx.y * BM;
    const int bn = blockIdx.x * BN;

    const float scale = *scale_p;

    // ---- ds_read per-thread bases (element units, swizzle folded in) ----
    // fragment: row-block base + (lane&15); k-quad (lane>>4)*8, XOR'd by
    // element-bit-4 when (lane&8) (== byte-bit5 ^= byte-bit9 of full addr).
    const int m15 = lane & 15;
    const int kqx = ((lane >> 4) << 3) ^ ((lane & 8) << 1);
    const int aRd = (wr * 64 + m15) * 32 + kqx;             // + rq*8192 + kc*4096 + rb*512
    const int bRd = 16384 + (wc * 32 + m15) * 32 + kqx;     // + cq*8192 + kc*4096 + cb*512

    // ---- staging source offsets (inverse swizzle on global source) ----
    // call c: linear dest element d0 = wave*1024 + c*512 + lane*8
    size_t offA0, offA1, offB0, offB1;
    {
        const int d0 = wave * 1024 + lane * 8;
        const int kc = d0 >> 12;
        const int r  = (d0 >> 5) & 127;
        const int cl = (d0 ^ (((d0 >> 8) & 1) << 4)) & 31;
        offA0 = (size_t)(bm + (r >> 6) * 128 + (r & 63)) * KK + kc * 32 + cl;
        offB0 = (size_t)(bn + (r >> 5) * 64 + (r & 31)) * KK + kc * 32 + cl;
        const int d1 = d0 + 512;
        const int kc1 = d1 >> 12;
        const int r1  = (d1 >> 5) & 127;
        const int cl1 = (d1 ^ (((d1 >> 8) & 1) << 4)) & 31;
        offA1 = (size_t)(bm + (r1 >> 6) * 128 + (r1 & 63)) * KK + kc1 * 32 + cl1;
        offB1 = (size_t)(bn + (r1 >> 5) * 64 + (r1 & 31)) * KK + kc1 * 32 + cl1;
    }
    const unsigned short* const Ag = A;
    const unsigned short* const Bg = B;

    floatx4 acc[2][4][2][2];    // [rq][rb][cq][cb]
#pragma unroll
    for (int rq = 0; rq < 2; ++rq)
#pragma unroll
        for (int rb = 0; rb < 4; ++rb)
#pragma unroll
            for (int cq = 0; cq < 2; ++cq)
#pragma unroll
                for (int cb = 0; cb < 2; ++cb)
                    acc[rq][rb][cq][cb] = (floatx4)0.0f;

    short8 a[4][2], b0[2][2], b1[2][2];

    // ---- prologue: tile0 -> buf0 (all 4 slots first!), tile1 -> buf1 (3 slots)
    STAGE_A(0, 0, 0); STAGE_A(0, 1, 0); STAGE_B(0, 0, 0); STAGE_B(0, 1, 0);
    STAGE_A(1, 0, 1); STAGE_B(1, 0, 1); STAGE_B(1, 1, 1);
    asm volatile("s_waitcnt vmcnt(6)" ::: "memory");   // tile0 fully landed
    BAR();

    for (int i = 0; i < NIT - 1; ++i) {
        const int t1 = 2 * i + 1, t2 = 2 * i + 2, t3 = 2 * i + 3;
        // ph1
        LDA(0, 0); LDB(0, 0, b0);
        STAGE_A(1, 1, t1);
        BAR(); WAIT_LGKM(); PRIO1(); MFMA_Q(0, 0, b0); PRIO0(); BAR();
        // ph2
        LDB(0, 1, b1);
        STAGE_A(0, 0, t2);
        BAR(); WAIT_LGKM(); PRIO1(); MFMA_Q(0, 1, b1); PRIO0(); BAR();
        // ph3
        LDA(0, 1);
        STAGE_B(0, 0, t2);
        BAR(); WAIT_LGKM(); PRIO1(); MFMA_Q(1, 0, b0); PRIO0(); BAR();
        // ph4
        STAGE_B(0, 1, t2);
        BAR(); WAIT_VM6(); PRIO1(); MFMA_Q(1, 1, b1); PRIO0(); BAR();
        // ph5
        LDA(32768, 0); LDB(32768, 0, b0);
        STAGE_A(0, 1, t2);
        BAR(); WAIT_LGKM(); PRIO1(); MFMA_Q(0, 0, b0); PRIO0(); BAR();
        // ph6
        LDB(32768, 1, b1);
        STAGE_A(1, 0, t3);
        BAR(); WAIT_LGKM(); PRIO1(); MFMA_Q(0, 1, b1); PRIO0(); BAR();
        // ph7
        LDA(32768, 1);
        STAGE_B(1, 0, t3);
        BAR(); WAIT_LGKM(); PRIO1(); MFMA_Q(1, 0, b0); PRIO0(); BAR();
        // ph8
        STAGE_B(1, 1, t3);
        BAR(); WAIT_VM6(); PRIO1(); MFMA_Q(1, 1, b1); PRIO0(); BAR();
    }
    // ---- peeled last iteration (tiles 62 in buf0, 63 in buf1) ----
    {
        // ph1 (last staging: buf1-A-h1 of tile 63)
        LDA(0, 0); LDB(0, 0, b0);
        STAGE_A(1, 1, KT - 1);
        BAR(); WAIT_LGKM(); PRIO1(); MFMA_Q(0, 0, b0); PRIO0(); BAR();
        // ph2
        LDB(0, 1, b1);
        BAR(); WAIT_LGKM(); PRIO1(); MFMA_Q(0, 1, b1); PRIO0(); BAR();
        // ph3
        LDA(0, 1);
        BAR(); WAIT_LGKM(); PRIO1(); MFMA_Q(1, 0, b0); PRIO0(); BAR();
        // ph4 — drain remaining staging before buf1 reads
        BAR(); WAIT_VM0(); PRIO1(); MFMA_Q(1, 1, b1); PRIO0(); BAR();
        // ph5
        LDA(32768, 0); LDB(32768, 0, b0);
        BAR(); WAIT_LGKM(); PRIO1(); MFMA_Q(0, 0, b0); PRIO0(); BAR();
        // ph6
        LDB(32768, 1, b1);
        BAR(); WAIT_LGKM(); PRIO1(); MFMA_Q(0, 1, b1); PRIO0(); BAR();
        // ph7
        LDA(32768, 1);
        BAR(); WAIT_LGKM(); PRIO1(); MFMA_Q(1, 0, b0); PRIO0(); BAR();
        // ph8
        WAIT_LGKM(); PRIO1(); MFMA_Q(1, 1, b1); PRIO0();
    }

    // ---- epilogue: C/D layout col=lane&15, row=(lane>>4)*4+reg ----
    const int crow = (lane >> 4) * 4;
    const int ccol = lane & 15;
#pragma unroll
    for (int rq = 0; rq < 2; ++rq)
#pragma unroll
    for (int rb = 0; rb < 4; ++rb)
#pragma unroll
    for (int cq = 0; cq < 2; ++cq)
#pragma unroll
    for (int cb = 0; cb < 2; ++cb) {
        const size_t rbase = (size_t)(bm + wr * 128 + rq * 64 + rb * 16 + crow) * NN
                           + (size_t)(bn + wc * 64 + cq * 32 + cb * 16 + ccol);
#pragma unroll
        for (int rg = 0; rg < 4; ++rg)
            C[rbase + (size_t)rg * NN] = acc[rq][rb][cq][cb][rg] * scale;
    }
}

extern "C" void kernel_launch(void* const* d_in, const int* in_sizes, int n_in,
                              void* d_out, int out_size, void* d_ws, size_t ws_size,
                              hipStream_t stream) {
    const float* x     = (const float*)d_in[0];   // [4,2048,4096] fp32
    const int*   w     = (const int*)d_in[1];     // [11008,4096] int32 (int8 range)
    const float* scale = (const float*)d_in[2];   // [1] fp32
    float* out = (float*)d_out;                   // [4,2048,11008] fp32

    // workspace: x_bf16 (64 MiB) then w_bf16 (86 MiB); total 150 MiB
    unsigned short* xb = (unsigned short*)d_ws;
    unsigned short* wb = xb + (size_t)MM * KK;

    cvt_x_kernel<<<(int)(((size_t)MM * KK) / 2048), 256, 0, stream>>>(x, xb);
    cvt_w_kernel<<<(int)(((size_t)NN * KK) / 2048), 256, 0, stream>>>(w, wb);

    dim3 grid(NN / BN, MM / BM);   // (43, 32)
    gemm_bt_bf16_8ph<<<grid, 512, 0, stream>>>(xb, wb, scale, out);
}